// Round 12
// baseline (1793.273 us; speedup 1.0000x reference)
//
#include <hip/hip_runtime.h>
#include <stdint.h>

// IPAttnProcessor on MI355X. (v3, resubmitted R12)
// Pipeline: split_all(fp32->bf16 hi/lo, one launch) -> Q-proj (split-bf16
//           MFMA GEMM) -> KV-proj (same kernel, 4-weight select) -> fused
//           dual-softmax attention (fp32 vector, K/V in LDS) -> O-proj GEMM
//           with bias+residual epilogue.
// Accuracy: 3-term split GEMM (hh, hl, lh) ~17 mantissa bits per input.
// Workspace: ~420 MB (Ahi/Alo alias Hhi/Hlo, dead after Q-proj).

typedef unsigned short u16;
typedef __attribute__((ext_vector_type(8))) short short8;
typedef __attribute__((ext_vector_type(4))) float f32x4;

__device__ __forceinline__ u16 f2bf_rn(float x){
  uint32_t u = __float_as_uint(x);
  return (u16)((u + 0x7FFFu + ((u >> 16) & 1u)) >> 16);
}

// ---------------- batched split: all tensors in ONE launch ----------------
// Segment map over float4 index space (compile-time boundaries):
//   [0,b1)   Wq     [b1,b2) Wo     [b2,b3) Wk     [b3,b4) Wv
//   [b4,b5)  Wkip   [b5,b6) Wvip   [b6,b7) ENC (zero-pad >= NES4)
//   [b7,b8)  H  (73% of work -> tested first)
#define NWQ4 409600
#define NWK4 655360
#define NES4 331776
#define NET4 393216
#define NH4  10485760
#define SB1 (NWQ4)
#define SB2 (SB1 + NWQ4)
#define SB3 (SB2 + NWK4)
#define SB4 (SB3 + NWK4)
#define SB5 (SB4 + NWK4)
#define SB6 (SB5 + NWK4)
#define SB7 (SB6 + NET4)
#define SB8 (SB7 + NH4)

__global__ __launch_bounds__(256) void split_all_kernel(
    const float* __restrict__ Wq,   const float* __restrict__ Wo,
    const float* __restrict__ Wk,   const float* __restrict__ Wv,
    const float* __restrict__ Wkip, const float* __restrict__ Wvip,
    const float* __restrict__ ENC,  const float* __restrict__ H,
    u16* __restrict__ Wqhi,  u16* __restrict__ Wqlo,
    u16* __restrict__ Wohi,  u16* __restrict__ Wolo,
    u16* __restrict__ Wkhi,  u16* __restrict__ Wklo,
    u16* __restrict__ Wvhi,  u16* __restrict__ Wvlo,
    u16* __restrict__ Wkiphi,u16* __restrict__ Wkiplo,
    u16* __restrict__ Wviphi,u16* __restrict__ Wviplo,
    u16* __restrict__ Ehi,   u16* __restrict__ Elo,
    u16* __restrict__ Hhi,   u16* __restrict__ Hlo)
{
  const int stride = gridDim.x * 256;
  for (int i = blockIdx.x * 256 + threadIdx.x; i < SB8; i += stride){
    const float* src; u16* hi; u16* lo; int li; bool zero = false;
    if (i >= SB7)      { src = H;    hi = Hhi;    lo = Hlo;    li = i - SB7; }
    else if (i < SB1)  { src = Wq;   hi = Wqhi;   lo = Wqlo;   li = i;       }
    else if (i < SB2)  { src = Wo;   hi = Wohi;   lo = Wolo;   li = i - SB1; }
    else if (i < SB3)  { src = Wk;   hi = Wkhi;   lo = Wklo;   li = i - SB2; }
    else if (i < SB4)  { src = Wv;   hi = Wvhi;   lo = Wvlo;   li = i - SB3; }
    else if (i < SB5)  { src = Wkip; hi = Wkiphi; lo = Wkiplo; li = i - SB4; }
    else if (i < SB6)  { src = Wvip; hi = Wviphi; lo = Wviplo; li = i - SB5; }
    else               { src = ENC;  hi = Ehi;    lo = Elo;    li = i - SB6;
                         zero = (li >= NES4); }
    ushort4 h = {0,0,0,0}, l = {0,0,0,0};
    if (!zero){
      float4 x = ((const float4*)src)[li];
      uint32_t bx = __float_as_uint(x.x), by = __float_as_uint(x.y),
               bz = __float_as_uint(x.z), bw = __float_as_uint(x.w);
      h.x = (u16)(bx >> 16); h.y = (u16)(by >> 16);
      h.z = (u16)(bz >> 16); h.w = (u16)(bw >> 16);
      l.x = f2bf_rn(x.x - __uint_as_float(bx & 0xFFFF0000u));
      l.y = f2bf_rn(x.y - __uint_as_float(by & 0xFFFF0000u));
      l.z = f2bf_rn(x.z - __uint_as_float(bz & 0xFFFF0000u));
      l.w = f2bf_rn(x.w - __uint_as_float(bw & 0xFFFF0000u));
    }
    ((ushort4*)hi)[li] = h;
    ((ushort4*)lo)[li] = l;
  }
}

// ---------------- async global->LDS 16B ----------------
__device__ __forceinline__ void async16(const void* g, void* l){
  __builtin_amdgcn_global_load_lds(
      (const __attribute__((address_space(1))) void*)g,
      (__attribute__((address_space(3))) void*)l, 16, 0, 0);
}

// ---------------- split-bf16 GEMM: C[M,N] = A[M,K] * B[N,K]^T ----------------
// MODE 0: plain (Q proj)   MODE 1: KV (B selected from 4 weights by n-block,
// N spans 4*1280)          MODE 2: out proj (+bias +residual)
// Tile 128x128, BK=32, 4 waves (2x2 of 64x64), 16x16x32 bf16 MFMA, 3 terms.
template<int MODE>
__global__ __launch_bounds__(256) void gemm_split(
    const u16* __restrict__ Ahi, const u16* __restrict__ Alo,
    const u16* __restrict__ B0h, const u16* __restrict__ B0l,
    const u16* __restrict__ B1h, const u16* __restrict__ B1l,
    const u16* __restrict__ B2h, const u16* __restrict__ B2l,
    const u16* __restrict__ B3h, const u16* __restrict__ B3l,
    float* __restrict__ C, int K, int N,
    const float* __restrict__ bias, const float* __restrict__ resid)
{
  __shared__ __align__(16) u16 lds[16384];  // Ahi | Alo | Bhi | Blo, 8KB each
  const int tid = (int)threadIdx.x;
  const int w = tid >> 6, l = tid & 63;
  const int wm = w >> 1, wn = w & 1;
  const int nb = (int)blockIdx.x, mb = (int)blockIdx.y;
  const int row0 = mb * 128;

  const u16 *Bh, *Bl;
  int bcol0;
  if (MODE == 1){
    const int mat = nb / 10;            // 1280/128 = 10 n-blocks per matrix
    bcol0 = (nb % 10) * 128;
    Bh = (mat == 0) ? B0h : (mat == 1) ? B1h : (mat == 2) ? B2h : B3h;
    Bl = (mat == 0) ? B0l : (mat == 1) ? B1l : (mat == 2) ? B2l : B3l;
  } else {
    Bh = B0h; Bl = B0l; bcol0 = nb * 128;
  }

  f32x4 acc[4][4];
#pragma unroll
  for (int i = 0; i < 4; ++i)
#pragma unroll
    for (int j = 0; j < 4; ++j)
      acc[i][j] = (f32x4){0.f, 0.f, 0.f, 0.f};

  // staging geometry: 8 chunks of 1KB per 8KB tile; wave w owns chunks w, w+4
  // lane l of chunk c stages global (row0 + c*16 + (l>>2), k0 + (l&3)*8 .. +8)
  // into LDS bytes c*1024 + l*16  == row-major [128][32] (verified identity).
  const int c0 = w, c1 = w + 4;
  const int ra = c0 * 16 + (l >> 2);
  const int rb = c1 * 16 + (l >> 2);
  const int kk = (l & 3) * 8;
  const size_t aoff0 = (size_t)(row0 + ra) * K + kk;
  const size_t aoff1 = (size_t)(row0 + rb) * K + kk;
  const size_t boff0 = (size_t)(bcol0 + ra) * K + kk;
  const size_t boff1 = (size_t)(bcol0 + rb) * K + kk;

  for (int k0 = 0; k0 < K; k0 += 32){
    __syncthreads();
    async16(Ahi + aoff0 + k0, &lds[0*4096 + c0*512]);
    async16(Ahi + aoff1 + k0, &lds[0*4096 + c1*512]);
    async16(Alo + aoff0 + k0, &lds[1*4096 + c0*512]);
    async16(Alo + aoff1 + k0, &lds[1*4096 + c1*512]);
    async16(Bh  + boff0 + k0, &lds[2*4096 + c0*512]);
    async16(Bh  + boff1 + k0, &lds[2*4096 + c1*512]);
    async16(Bl  + boff0 + k0, &lds[3*4096 + c0*512]);
    async16(Bl  + boff1 + k0, &lds[3*4096 + c1*512]);
    __syncthreads();

    short8 ah[4], al[4], bh[4], bl[4];
#pragma unroll
    for (int f = 0; f < 4; ++f){
      const int ao = (wm*64 + f*16 + (l & 15)) * 32 + (l >> 4) * 8;
      const int bo = (wn*64 + f*16 + (l & 15)) * 32 + (l >> 4) * 8;
      ah[f] = *(const short8*)&lds[0*4096 + ao];
      al[f] = *(const short8*)&lds[1*4096 + ao];
      bh[f] = *(const short8*)&lds[2*4096 + bo];
      bl[f] = *(const short8*)&lds[3*4096 + bo];
    }
#pragma unroll
    for (int i = 0; i < 4; ++i)
#pragma unroll
      for (int j = 0; j < 4; ++j){
        acc[i][j] = __builtin_amdgcn_mfma_f32_16x16x32_bf16(ah[i], bh[j], acc[i][j], 0, 0, 0);
        acc[i][j] = __builtin_amdgcn_mfma_f32_16x16x32_bf16(ah[i], bl[j], acc[i][j], 0, 0, 0);
        acc[i][j] = __builtin_amdgcn_mfma_f32_16x16x32_bf16(al[i], bh[j], acc[i][j], 0, 0, 0);
      }
  }

  // epilogue: C/D layout col=lane&15, row=(lane>>4)*4+reg  [m89-verified]
  const int crow0 = row0 + wm*64 + (l >> 4) * 4;
  const int ccol0 = nb*128 + wn*64 + (l & 15);
#pragma unroll
  for (int i = 0; i < 4; ++i)
#pragma unroll
    for (int j = 0; j < 4; ++j){
      const int col = ccol0 + j*16;
      float bv = 0.f;
      if (MODE == 2) bv = bias[col];
#pragma unroll
      for (int r = 0; r < 4; ++r){
        const int row = crow0 + i*16 + r;
        const size_t idx = (size_t)row * N + col;
        float v = acc[i][j][r];
        if (MODE == 2) v += bv + resid[idx];
        C[idx] = v;
      }
    }
}

// ---------------- fused dual-softmax attention ----------------
// One thread = one query row. K/V text (77x64) + ip (4x64) staged in LDS
// (all lanes read the same element -> LDS broadcast, conflict-free).
// Two independent softmaxes (text over 77, ip over 4), shared PV accumulator
// (IP_SCALE = 1). Writes hi/lo bf16 split for the O-proj GEMM.
__global__ __launch_bounds__(256) void attn_kernel(
    const float* __restrict__ Q, const float* __restrict__ KV,
    u16* __restrict__ Ohi, u16* __restrict__ Olo)
{
  const int tid = (int)threadIdx.x;
  const int chunk = (int)blockIdx.x, h = (int)blockIdx.y, b = (int)blockIdx.z;
  __shared__ __align__(16) float sK[77*64];
  __shared__ __align__(16) float sV[77*64];
  __shared__ __align__(16) float sKip[4*64];
  __shared__ __align__(16) float sVip[4*64];

  const size_t kvbase = (size_t)b * 81 * 5120 + (size_t)h * 64;
  for (int idx = tid; idx < 77*16; idx += 256){
    const int ll = idx >> 4, d4 = (idx & 15) * 4;
    *(float4*)&sK[ll*64 + d4] = *(const float4*)&KV[kvbase + (size_t)ll*5120 + d4];
    *(float4*)&sV[ll*64 + d4] = *(const float4*)&KV[kvbase + (size_t)ll*5120 + 1280 + d4];
  }
  if (tid < 64){
    const int ll = tid >> 4, d4 = (tid & 15) * 4;
    *(float4*)&sKip[ll*64 + d4] = *(const float4*)&KV[kvbase + (size_t)(77+ll)*5120 + 2560 + d4];
    *(float4*)&sVip[ll*64 + d4] = *(const float4*)&KV[kvbase + (size_t)(77+ll)*5120 + 3840 + d4];
  }
  __syncthreads();

  const int row = chunk * 256 + tid;
  const size_t qoff = ((size_t)b * 4096 + row) * 1280 + (size_t)h * 64;

  float4 q4[16];
#pragma unroll
  for (int i = 0; i < 16; ++i) q4[i] = *(const float4*)&Q[qoff + i*4];

  const float4* K4 = (const float4*)sK;
  float s[77];
#pragma unroll
  for (int t = 0; t < 77; ++t){
    float a = 0.f;
#pragma unroll
    for (int i = 0; i < 16; ++i){
      const float4 k = K4[t*16 + i];
      a = fmaf(q4[i].x, k.x, a); a = fmaf(q4[i].y, k.y, a);
      a = fmaf(q4[i].z, k.z, a); a = fmaf(q4[i].w, k.w, a);
    }
    s[t] = a * 0.125f;
  }
  const float4* Kip4 = (const float4*)sKip;
  float sip[4];
#pragma unroll
  for (int t = 0; t < 4; ++t){
    float a = 0.f;
#pragma unroll
    for (int i = 0; i < 16; ++i){
      const float4 k = Kip4[t*16 + i];
      a = fmaf(q4[i].x, k.x, a); a = fmaf(q4[i].y, k.y, a);
      a = fmaf(q4[i].z, k.z, a); a = fmaf(q4[i].w, k.w, a);
    }
    sip[t] = a * 0.125f;
  }

  // softmax (text)
  float m = s[0];
#pragma unroll
  for (int t = 1; t < 77; ++t) m = fmaxf(m, s[t]);
  float sum = 0.f;
#pragma unroll
  for (int t = 0; t < 77; ++t){ s[t] = __expf(s[t] - m); sum += s[t]; }
  const float inv = 1.0f / sum;
#pragma unroll
  for (int t = 0; t < 77; ++t) s[t] *= inv;

  // softmax (ip)
  float m2 = fmaxf(fmaxf(sip[0], sip[1]), fmaxf(sip[2], sip[3]));
  float sum2 = 0.f;
#pragma unroll
  for (int t = 0; t < 4; ++t){ sip[t] = __expf(sip[t] - m2); sum2 += sip[t]; }
  const float inv2 = 1.0f / sum2;
#pragma unroll
  for (int t = 0; t < 4; ++t) sip[t] *= inv2;

  // PV (shared accumulator; IP_SCALE = 1)
  float4 o4[16];
#pragma unroll
  for (int i = 0; i < 16; ++i) o4[i] = (float4){0.f, 0.f, 0.f, 0.f};
  const float4* V4 = (const float4*)sV;
#pragma unroll
  for (int t = 0; t < 77; ++t){
    const float p = s[t];
#pragma unroll
    for (int i = 0; i < 16; ++i){
      const float4 v = V4[t*16 + i];
      o4[i].x = fmaf(p, v.x, o4[i].x); o4[i].y = fmaf(p, v.y, o4[i].y);
      o4[i].z = fmaf(p, v.z, o4[i].z); o4[i].w = fmaf(p, v.w, o4[i].w);
    }
  }
  const float4* Vip4 = (const float4*)sVip;
#pragma unroll
  for (int t = 0; t < 4; ++t){
    const float p = sip[t];
#pragma unroll
    for (int i = 0; i < 16; ++i){
      const float4 v = Vip4[t*16 + i];
      o4[i].x = fmaf(p, v.x, o4[i].x); o4[i].y = fmaf(p, v.y, o4[i].y);
      o4[i].z = fmaf(p, v.z, o4[i].z); o4[i].w = fmaf(p, v.w, o4[i].w);
    }
  }

  // write hi/lo bf16 split
#pragma unroll
  for (int i = 0; i < 16; ++i){
    const float vx = o4[i].x, vy = o4[i].y, vz = o4[i].z, vw = o4[i].w;
    const uint32_t ux = __float_as_uint(vx), uy = __float_as_uint(vy),
                   uz = __float_as_uint(vz), uw = __float_as_uint(vw);
    ushort4 hv, lv;
    hv.x = (u16)(ux >> 16); hv.y = (u16)(uy >> 16);
    hv.z = (u16)(uz >> 16); hv.w = (u16)(uw >> 16);
    lv.x = f2bf_rn(vx - __uint_as_float(ux & 0xFFFF0000u));
    lv.y = f2bf_rn(vy - __uint_as_float(uy & 0xFFFF0000u));
    lv.z = f2bf_rn(vz - __uint_as_float(uz & 0xFFFF0000u));
    lv.w = f2bf_rn(vw - __uint_as_float(uw & 0xFFFF0000u));
    *(ushort4*)&Ohi[qoff + i*4] = hv;
    *(ushort4*)&Olo[qoff + i*4] = lv;
  }
}

// ---------------- host ----------------
extern "C" void kernel_launch(void* const* d_in, const int* in_sizes, int n_in,
                              void* d_out, int out_size, void* d_ws, size_t ws_size,
                              hipStream_t stream)
{
  (void)in_sizes; (void)n_in; (void)out_size;
  const float* H    = (const float*)d_in[0];  // (8,4096,1280)
  const float* ENC  = (const float*)d_in[1];  // (8,81,2048)
  const float* Wq   = (const float*)d_in[2];  // (1280,1280)
  const float* Wk   = (const float*)d_in[3];  // (1280,2048)
  const float* Wv   = (const float*)d_in[4];
  const float* Wkip = (const float*)d_in[5];
  const float* Wvip = (const float*)d_in[6];
  const float* Wo   = (const float*)d_in[7];  // (1280,1280)
  const float* bo   = (const float*)d_in[8];  // (1280,)

  const int nH   = 8*4096*1280;      // 41,943,040
  const int nWq  = 1280*1280;        // 1,638,400
  const int nWk  = 1280*2048;        // 2,621,440
  const int nEt  = 768*2048;         // 1,572,864 (padded to 768 rows)
  const int nKV  = 768*5120;         // 3,932,160

  char* ws = (char*)d_ws;
  size_t off = 0;
  auto alloc = [&](size_t bytes) -> void* {
    void* p = ws + off; off += (bytes + 255) & ~(size_t)255; return p;
  };
  // Hhi/Hlo double as Ahi/Alo: the H-split is consumed only by gemm<0>
  // (Q-proj); attn_kernel overwrites it afterwards (stream-ordered).
  u16* Hhi  = (u16*)alloc((size_t)nH*2);   u16* Hlo  = (u16*)alloc((size_t)nH*2);
  u16* Wqhi = (u16*)alloc((size_t)nWq*2);  u16* Wqlo = (u16*)alloc((size_t)nWq*2);
  u16* Wohi = (u16*)alloc((size_t)nWq*2);  u16* Wolo = (u16*)alloc((size_t)nWq*2);
  u16* Wkhi = (u16*)alloc((size_t)nWk*2);  u16* Wklo = (u16*)alloc((size_t)nWk*2);
  u16* Wvhi = (u16*)alloc((size_t)nWk*2);  u16* Wvlo = (u16*)alloc((size_t)nWk*2);
  u16* Wkiphi = (u16*)alloc((size_t)nWk*2); u16* Wkiplo = (u16*)alloc((size_t)nWk*2);
  u16* Wviphi = (u16*)alloc((size_t)nWk*2); u16* Wviplo = (u16*)alloc((size_t)nWk*2);
  u16* Ehi  = (u16*)alloc((size_t)nEt*2);  u16* Elo  = (u16*)alloc((size_t)nEt*2);
  float* Qb   = (float*)alloc((size_t)nH*4);
  float* KVb  = (float*)alloc((size_t)nKV*4);
  u16* Ahi = Hhi;  u16* Alo = Hlo;   // alias (saves 160 MB)
  // total ws used: ~420 MB

  if (ws_size < off) return;  // workspace too small: bail loudly (validation
                              // will fail on poisoned d_out) instead of OOB.

  // all hi/lo splits in one launch (weights + ENC(padded) + H)
  split_all_kernel<<<dim3(2048), dim3(256), 0, stream>>>(
      Wq, Wo, Wk, Wv, Wkip, Wvip, ENC, H,
      Wqhi, Wqlo, Wohi, Wolo, Wkhi, Wklo, Wvhi, Wvlo,
      Wkiphi, Wkiplo, Wviphi, Wviplo, Ehi, Elo, Hhi, Hlo);

  // Q = H @ Wq^T   (M=32768, N=1280, K=1280)
  gemm_split<0><<<dim3(10, 256), dim3(256), 0, stream>>>(
      Hhi, Hlo, Wqhi, Wqlo, nullptr, nullptr, nullptr, nullptr, nullptr, nullptr,
      Qb, 1280, 1280, nullptr, nullptr);

  // KV = ENCpad @ [Wk|Wv|Wkip|Wvip]^T  (M=768, N=5120, K=2048)
  gemm_split<1><<<dim3(40, 6), dim3(256), 0, stream>>>(
      Ehi, Elo, Wkhi, Wklo, Wvhi, Wvlo, Wkiphi, Wkiplo, Wviphi, Wviplo,
      KVb, 2048, 5120, nullptr, nullptr);

  // attention: grid (4096/256, heads, batch); writes Ahi/Alo (= Hhi/Hlo mem)
  attn_kernel<<<dim3(16, 20, 8), dim3(256), 0, stream>>>(Qb, KVb, Ahi, Alo);

  // out = attn @ Wo^T + bo + H   (M=32768, N=1280, K=1280)
  gemm_split<2><<<dim3(10, 256), dim3(256), 0, stream>>>(
      Ahi, Alo, Wohi, Wolo, nullptr, nullptr, nullptr, nullptr, nullptr, nullptr,
      (float*)d_out, 1280, 1280, bo, H);
}